// Round 4
// baseline (71.981 us; speedup 1.0000x reference)
//
#include <hip/hip_runtime.h>
#include <hip/hip_bf16.h>
#include <math.h>

#define N_PTS 16384
#define KNN   16
#define NCLS  20
#define BND_W 1.0f

#define THREADS 512
#define WAVES   8
#define FR      4                    // A fragments per wave (16 rows each)
#define RPW     (16 * FR)            // 64 rows per wave
#define RPB     (WAVES * RPW)        // 512 rows per block
#define RBLKS   (N_PTS / RPB)        // 32
#define CPB     512                  // candidates per block (one LDS chunk)
#define CSPLIT  (N_PTS / CPB)        // 32

typedef short  short8 __attribute__((ext_vector_type(8)));
typedef float  f32x4  __attribute__((ext_vector_type(4)));

// ---- float <-> order-preserving uint (atomicMax over possibly-negative f32) ----
__device__ __forceinline__ unsigned enc_f(float f) {
    unsigned b = __float_as_uint(f);
    return (b & 0x80000000u) ? ~b : (b | 0x80000000u);
}
__device__ __forceinline__ float dec_f(unsigned u) {
    unsigned b = (u & 0x80000000u) ? (u ^ 0x80000000u) : ~u;
    return __uint_as_float(b);
}

// ---- bf16 helpers (RNE) ----
__device__ __forceinline__ unsigned short f2bf(float x) {
    union { __hip_bfloat16 h; unsigned short u; } cv;
    cv.h = __float2bfloat16(x);
    return cv.u;
}
__device__ __forceinline__ float bf2f(unsigned short b) {
    union { __hip_bfloat16 h; unsigned short u; } cv;
    cv.u = b;
    return __bfloat162float(cv.h);
}

// Candidate encoding (B operand), 32 bf16 slots:
//  0..8: (xh,xh,xl)(yh,yh,yl)(zh,zh,zl); 9,10: -h_hi,-h_lo (h=0.5|v|^2);
//  11..30: one-hot(label)=1.0; 31: 1.0 iff label==-1
__device__ __forceinline__ void build_b(const float* __restrict__ coord,
                                        const int* __restrict__ seg, int j,
                                        unsigned short* out) {
    float x = coord[3 * j], y = coord[3 * j + 1], z = coord[3 * j + 2];
    int lab = seg[j];
    unsigned short xh = f2bf(x), yh = f2bf(y), zh = f2bf(z);
    unsigned short xl = f2bf(x - bf2f(xh));
    unsigned short yl = f2bf(y - bf2f(yh));
    unsigned short zl = f2bf(z - bf2f(zh));
    float h = 0.5f * fmaf(x, x, fmaf(y, y, z * z));
    unsigned short hh = f2bf(h);
    unsigned short hl = f2bf(h - bf2f(hh));
    out[0] = xh; out[1] = xh; out[2] = xl;
    out[3] = yh; out[4] = yh; out[5] = yl;
    out[6] = zh; out[7] = zh; out[8] = zl;
    out[9]  = hh ^ 0x8000u;
    out[10] = hl ^ 0x8000u;
#pragma unroll
    for (int s = 0; s < NCLS; s++) out[11 + s] = (lab == s) ? 0x3F80u : 0u;
    out[31] = (lab < 0) ? 0x3F80u : 0u;
}

// Center encoding (A operand): coords (xh,xl,xh)...; 9,10 = 1.0;
// PASS1: -1024 at own class slot + slot31; PASS2: label slots zero.
// Coord/h slots identical across passes -> bit-identical geometric scores.
template<bool PASS1>
__device__ __forceinline__ void build_a(const float* __restrict__ coord,
                                        const int* __restrict__ seg, int i,
                                        unsigned short* out) {
    float x = coord[3 * i], y = coord[3 * i + 1], z = coord[3 * i + 2];
    int lab = seg[i];
    unsigned short xh = f2bf(x), yh = f2bf(y), zh = f2bf(z);
    unsigned short xl = f2bf(x - bf2f(xh));
    unsigned short yl = f2bf(y - bf2f(yh));
    unsigned short zl = f2bf(z - bf2f(zh));
    out[0] = xh; out[1] = xl; out[2] = xh;
    out[3] = yh; out[4] = yl; out[5] = yh;
    out[6] = zh; out[7] = zl; out[8] = zh;
    out[9] = 0x3F80u; out[10] = 0x3F80u;
    const unsigned short nb = 0xC480u;   // bf16(-1024.0)
#pragma unroll
    for (int s = 0; s < NCLS; s++) out[11 + s] = (PASS1 && lab == s) ? nb : 0u;
    out[31] = PASS1 ? nb : 0u;
}

__global__ __launch_bounds__(256) void k_init(unsigned* __restrict__ smax_enc,
                                              int* __restrict__ cnt,
                                              float* __restrict__ accum,
                                              unsigned* __restrict__ done) {
    int i = blockIdx.x * 256 + threadIdx.x;
    smax_enc[i] = enc_f(-3.0e38f);
    cnt[i] = 0;
    if (i < 4) accum[i] = 0.f;
    if (i == 4) *done = 0u;
}

// Score matrix S[i][j] = a_i . b_j via mfma 16x16x32 bf16.
// PASS1: row-max over diff-labeled (others pushed to ~-1024).
// PASS2: row-count of s strictly greater than row threshold.
template<bool PASS1>
__global__ __launch_bounds__(THREADS) void k_pass(const float* __restrict__ coord,
                                                  const int* __restrict__ seg,
                                                  unsigned* __restrict__ smax_enc,
                                                  int* __restrict__ cnt) {
    __shared__ __align__(16) unsigned short smem[CPB * 32];  // 32 KB (A then B)
    const int tid  = threadIdx.x;
    const int lane = tid & 63, wave = tid >> 6;
    const int l15  = lane & 15, l4 = lane >> 4;
    const int rb   = blockIdx.x * RPB;
    const int cb   = blockIdx.y * CPB;

    // ---- thresholds (pass 2) ----
    float thr[FR][4];
    int   cv[FR][4];
    f32x4 rmax[FR];
    if (PASS1) {
#pragma unroll
        for (int f = 0; f < FR; f++)
#pragma unroll
            for (int r = 0; r < 4; r++) rmax[f][r] = -3.0e38f;
    } else {
#pragma unroll
        for (int f = 0; f < FR; f++) {
            int row0 = rb + wave * RPW + f * 16 + l4 * 4;
#pragma unroll
            for (int r = 0; r < 4; r++) {
                thr[f][r] = dec_f(smax_enc[row0 + r]);
                cv[f][r] = 0;
            }
        }
    }

    // ---- build A encodings in LDS, load fragments (RPB == THREADS) ----
    build_a<PASS1>(coord, seg, rb + tid, &smem[tid * 32]);
    __syncthreads();
    short8 af[FR];
    {
        const short8* ap = (const short8*)smem;
#pragma unroll
        for (int f = 0; f < FR; f++)
            af[f] = ap[(wave * RPW + f * 16 + l15) * 4 + l4];
    }
    __syncthreads();

    // ---- build B encodings (XOR-swizzled), CPB == THREADS ----
    {
        __attribute__((aligned(16))) unsigned short be[32];
        build_b(coord, seg, cb + tid, be);
        short8* wp = (short8*)smem;
        int swz = (tid >> 1) & 3;
#pragma unroll
        for (int kb = 0; kb < 4; kb++)
            wp[tid * 4 + (kb ^ swz)] = ((const short8*)be)[kb];
    }
    __syncthreads();

    // ---- sweep: per 32 candidates: 2 ds_read_b128 + 8 MFMA + 16 max3/32 cmp-add ----
    const short8* bp = (const short8*)smem;
    const int bidx = l15 * 4 + (l4 ^ ((l15 >> 1) & 3));
    const f32x4 zero = {0.f, 0.f, 0.f, 0.f};

#pragma unroll 2
    for (int c0 = 0; c0 < CPB; c0 += 32) {
        short8 bA = bp[bidx + c0 * 4];
        short8 bB = bp[bidx + (c0 + 16) * 4];
        f32x4 dA[FR], dB[FR];
#pragma unroll
        for (int f = 0; f < FR; f++)
            dA[f] = __builtin_amdgcn_mfma_f32_16x16x32_bf16(af[f], bA, zero, 0, 0, 0);
#pragma unroll
        for (int f = 0; f < FR; f++)
            dB[f] = __builtin_amdgcn_mfma_f32_16x16x32_bf16(af[f], bB, zero, 0, 0, 0);
        if (PASS1) {
#pragma unroll
            for (int f = 0; f < FR; f++)
#pragma unroll
                for (int r = 0; r < 4; r++)
                    rmax[f][r] = fmaxf(fmaxf(rmax[f][r], dA[f][r]), dB[f][r]);
        } else {
#pragma unroll
            for (int f = 0; f < FR; f++)
#pragma unroll
                for (int r = 0; r < 4; r++)
                    cv[f][r] += ((dA[f][r] > thr[f][r]) ? 1 : 0)
                              + ((dB[f][r] > thr[f][r]) ? 1 : 0);
        }
    }

    // ---- reduce across 16 column-lanes, merge across candidate splits ----
    if (PASS1) {
#pragma unroll
        for (int m = 1; m < 16; m <<= 1)
#pragma unroll
            for (int f = 0; f < FR; f++)
#pragma unroll
                for (int r = 0; r < 4; r++)
                    rmax[f][r] = fmaxf(rmax[f][r], __shfl_xor(rmax[f][r], m, 64));
        if (l15 == 0) {
#pragma unroll
            for (int f = 0; f < FR; f++) {
                int row0 = rb + wave * RPW + f * 16 + l4 * 4;
#pragma unroll
                for (int r = 0; r < 4; r++)
                    atomicMax(&smax_enc[row0 + r], enc_f(rmax[f][r]));
            }
        }
    } else {
#pragma unroll
        for (int m = 1; m < 16; m <<= 1)
#pragma unroll
            for (int f = 0; f < FR; f++)
#pragma unroll
                for (int r = 0; r < 4; r++)
                    cv[f][r] += __shfl_xor(cv[f][r], m, 64);
        if (l15 == 0) {
#pragma unroll
            for (int f = 0; f < FR; f++) {
                int row0 = rb + wave * RPW + f * 16 + l4 * 4;
#pragma unroll
                for (int r = 0; r < 4; r++)
                    atomicAdd(&cnt[row0 + r], cv[f][r]);
            }
        }
    }
}

__device__ __forceinline__ float waveReduceSum(float v) {
#pragma unroll
    for (int off = 32; off > 0; off >>= 1) v += __shfl_down(v, off, 64);
    return v;
}

// CE + masked accumulation; last block finalizes the loss (done-counter).
// accum: [0]=sum_main, [1]=cnt_main, [2]=sum_bnd, [3]=cnt_bnd
__global__ __launch_bounds__(256) void k_ce(const float* __restrict__ logits,
                                            const int* __restrict__ seg,
                                            const int* __restrict__ cnt,
                                            float* __restrict__ accum,
                                            unsigned* __restrict__ done,
                                            float* __restrict__ out) {
    const int i = blockIdx.x * 256 + threadIdx.x;
    float s_main = 0.f, n_main = 0.f, s_bnd = 0.f, n_bnd = 0.f;
    {
        int s = seg[i];
        bool valid = (s != -1);
        // 20-float row, 80 B, 16B-aligned -> 5 float4 loads
        const float4* row4 = (const float4*)(logits + (size_t)i * NCLS);
        float a[NCLS];
        float4 v0 = row4[0], v1 = row4[1], v2 = row4[2], v3 = row4[3], v4 = row4[4];
        a[0]=v0.x; a[1]=v0.y; a[2]=v0.z; a[3]=v0.w;
        a[4]=v1.x; a[5]=v1.y; a[6]=v1.z; a[7]=v1.w;
        a[8]=v2.x; a[9]=v2.y; a[10]=v2.z; a[11]=v2.w;
        a[12]=v3.x; a[13]=v3.y; a[14]=v3.z; a[15]=v3.w;
        a[16]=v4.x; a[17]=v4.y; a[18]=v4.z; a[19]=v4.w;
        float m = a[0];
#pragma unroll
        for (int c = 1; c < NCLS; c++) m = fmaxf(m, a[c]);
        float se = 0.f;
#pragma unroll
        for (int c = 0; c < NCLS; c++) se += __expf(a[c] - m);
        int tgt = min(max(s, 0), NCLS - 1);
        float at = 0.f;
#pragma unroll
        for (int c = 0; c < NCLS; c++) at += (c == tgt) ? a[c] : 0.f;
        float logp = at - m - __logf(se);
        bool bnd = valid && ((cnt[i] - 1) < KNN);
        if (valid) { s_main = logp; n_main = 1.f; }
        if (bnd)   { s_bnd  = logp; n_bnd  = 1.f; }
    }
    s_main = waveReduceSum(s_main);
    n_main = waveReduceSum(n_main);
    s_bnd  = waveReduceSum(s_bnd);
    n_bnd  = waveReduceSum(n_bnd);
    if ((threadIdx.x & 63) == 0) {
        atomicAdd(&accum[0], s_main);
        atomicAdd(&accum[1], n_main);
        atomicAdd(&accum[2], s_bnd);
        atomicAdd(&accum[3], n_bnd);
    }
    __syncthreads();
    if (threadIdx.x == 0) {
        __threadfence();
        unsigned old = atomicAdd(done, 1u);
        if (old == gridDim.x - 1) {
            // coherent reads of fully-accumulated values
            float sm = atomicAdd(&accum[0], 0.f);
            float cm = atomicAdd(&accum[1], 0.f);
            float sb = atomicAdd(&accum[2], 0.f);
            float cb = atomicAdd(&accum[3], 0.f);
            float main_loss = (cm > 0.f) ? (-sm / fmaxf(cm, 1.f)) : 0.f;
            float bnd_loss  = (cb > 0.f) ? (-sb / fmaxf(cb, 1.f)) : 0.f;
            out[0] = main_loss + BND_W * bnd_loss;
        }
    }
}

extern "C" void kernel_launch(void* const* d_in, const int* in_sizes, int n_in,
                              void* d_out, int out_size, void* d_ws, size_t ws_size,
                              hipStream_t stream) {
    const float* coord  = (const float*)d_in[0];
    const float* logits = (const float*)d_in[1];
    const int*   seg    = (const int*)d_in[2];
    (void)in_sizes; (void)n_in; (void)out_size; (void)ws_size;

    unsigned* smax_enc = (unsigned*)d_ws;                           // N u32
    int*      cnt      = (int*)((char*)d_ws + N_PTS * 4);           // N i32
    float*    accum    = (float*)((char*)d_ws + 2 * N_PTS * 4);     // 4 f32
    unsigned* done     = (unsigned*)((char*)d_ws + 2 * N_PTS * 4 + 16);

    dim3 grid(RBLKS, CSPLIT);
    k_init       <<<N_PTS / 256, 256, 0, stream>>>(smax_enc, cnt, accum, done);
    k_pass<true> <<<grid, THREADS, 0, stream>>>(coord, seg, smax_enc, cnt);
    k_pass<false><<<grid, THREADS, 0, stream>>>(coord, seg, smax_enc, cnt);
    k_ce         <<<N_PTS / 256, 256, 0, stream>>>(logits, seg, cnt, accum, done, (float*)d_out);
}

// Round 5
// 64.329 us; speedup vs baseline: 1.1190x; 1.1190x over previous
//
#include <hip/hip_runtime.h>
#include <hip/hip_bf16.h>
#include <math.h>

#define N_PTS 16384
#define KNN   16
#define NCLS  20
#define BND_W 1.0f

#define THREADS 512
#define WAVES   8
#define RPW     32                   // rows per wave (2 fragments of 16)
#define RPB     (WAVES * RPW)        // 256 rows per block
#define RBLKS   (N_PTS / RPB)        // 64
#define CSPLIT  16
#define CAND_PB (N_PTS / CSPLIT)     // 1024 candidates per block
#define CHUNK   512                  // candidates per LDS stage (32 KB)
#define NCHUNK  (CAND_PB / CHUNK)    // 2

typedef short  short8 __attribute__((ext_vector_type(8)));
typedef float  f32x4  __attribute__((ext_vector_type(4)));

// ---- bf16 helpers (RNE) ----
__device__ __forceinline__ unsigned short f2bf(float x) {
    union { __hip_bfloat16 h; unsigned short u; } cv;
    cv.h = __float2bfloat16(x);
    return cv.u;
}
__device__ __forceinline__ float bf2f(unsigned short b) {
    union { __hip_bfloat16 h; unsigned short u; } cv;
    cv.u = b;
    return __bfloat162float(cv.h);
}

// Candidate encoding (B operand), 32 bf16 slots:
//  0..8: (xh,xh,xl)(yh,yh,yl)(zh,zh,zl); 9,10: -h_hi,-h_lo (h=0.5|v|^2);
//  11..30: one-hot(label)=1.0; 31: 1.0 iff label==-1
__device__ __forceinline__ void build_b(const float* __restrict__ coord,
                                        const int* __restrict__ seg, int j,
                                        unsigned short* out) {
    float x = coord[3 * j], y = coord[3 * j + 1], z = coord[3 * j + 2];
    int lab = seg[j];
    unsigned short xh = f2bf(x), yh = f2bf(y), zh = f2bf(z);
    unsigned short xl = f2bf(x - bf2f(xh));
    unsigned short yl = f2bf(y - bf2f(yh));
    unsigned short zl = f2bf(z - bf2f(zh));
    float h = 0.5f * fmaf(x, x, fmaf(y, y, z * z));
    unsigned short hh = f2bf(h);
    unsigned short hl = f2bf(h - bf2f(hh));
    out[0] = xh; out[1] = xh; out[2] = xl;
    out[3] = yh; out[4] = yh; out[5] = yl;
    out[6] = zh; out[7] = zh; out[8] = zl;
    out[9]  = hh ^ 0x8000u;
    out[10] = hl ^ 0x8000u;
#pragma unroll
    for (int s = 0; s < NCLS; s++) out[11 + s] = (lab == s) ? 0x3F80u : 0u;
    out[31] = (lab < 0) ? 0x3F80u : 0u;
}

// Center encoding (A operand): coords (xh,xl,xh)...; 9,10 = 1.0;
// PASS1: -1024 at own class slot + slot31; PASS2: label slots zero.
// Coord/h slots identical across passes -> bit-identical geometric scores.
template<bool PASS1>
__device__ __forceinline__ void build_a(const float* __restrict__ coord,
                                        const int* __restrict__ seg, int i,
                                        unsigned short* out) {
    float x = coord[3 * i], y = coord[3 * i + 1], z = coord[3 * i + 2];
    int lab = seg[i];
    unsigned short xh = f2bf(x), yh = f2bf(y), zh = f2bf(z);
    unsigned short xl = f2bf(x - bf2f(xh));
    unsigned short yl = f2bf(y - bf2f(yh));
    unsigned short zl = f2bf(z - bf2f(zh));
    out[0] = xh; out[1] = xl; out[2] = xh;
    out[3] = yh; out[4] = yl; out[5] = yh;
    out[6] = zh; out[7] = zl; out[8] = zh;
    out[9] = 0x3F80u; out[10] = 0x3F80u;
    const unsigned short nb = 0xC480u;   // bf16(-1024.0)
#pragma unroll
    for (int s = 0; s < NCLS; s++) out[11 + s] = (PASS1 && lab == s) ? nb : 0u;
    out[31] = PASS1 ? nb : 0u;
}

// Score matrix S[i][j] = a_i . b_j via mfma 16x16x32 bf16.
// PASS1: per-(row,split) max over diff-labeled -> smax_part[split][row].
// PASS2: per-(row,split) count of s > row-threshold -> cnt_part[split][row].
template<bool PASS1>
__global__ __launch_bounds__(THREADS, 6) void k_pass(const float* __restrict__ coord,
                                                     const int* __restrict__ seg,
                                                     float* __restrict__ smax_part,
                                                     int* __restrict__ cnt_part,
                                                     float* __restrict__ accum,
                                                     unsigned* __restrict__ done) {
    __shared__ __align__(16) unsigned short smem[CHUNK * 32];  // 32 KB
    __shared__ float thr_lds[RPB];
    const int tid  = threadIdx.x;
    const int lane = tid & 63, wave = tid >> 6;
    const int l15  = lane & 15, l4 = lane >> 4;
    const int rb   = blockIdx.x * RPB;
    const int split = blockIdx.y;
    const int cb   = split * CAND_PB;

    if (PASS1 && blockIdx.x == 0 && split == 0 && tid == 0) {
        accum[0] = 0.f; accum[1] = 0.f; accum[2] = 0.f; accum[3] = 0.f;
        *done = 0u;
    }

    // ---- pass2 prologue: per-row threshold = max over the 16 split partials ----
    if (!PASS1 && tid < RPB) {
        int row = rb + tid;
        float m = smax_part[row];
#pragma unroll
        for (int s = 1; s < CSPLIT; s++) m = fmaxf(m, smax_part[s * N_PTS + row]);
        thr_lds[tid] = m;
    }

    // ---- build A encodings in LDS, load fragments ----
    if (tid < RPB) build_a<PASS1>(coord, seg, rb + tid, &smem[tid * 32]);
    __syncthreads();
    short8 af0, af1;
    {
        const short8* ap = (const short8*)smem;
        int r0 = wave * RPW + l15;
        af0 = ap[r0 * 4 + l4];
        af1 = ap[(r0 + 16) * 4 + l4];
    }
    float thr0[4], thr1[4];
    if (!PASS1) {
#pragma unroll
        for (int r = 0; r < 4; r++) {
            thr0[r] = thr_lds[wave * RPW + l4 * 4 + r];
            thr1[r] = thr_lds[wave * RPW + 16 + l4 * 4 + r];
        }
    }
    __syncthreads();

    f32x4 rmax0, rmax1;
    int cv0[4], cv1[4];
#pragma unroll
    for (int r = 0; r < 4; r++) {
        rmax0[r] = -3.0e38f; rmax1[r] = -3.0e38f;
        cv0[r] = 0; cv1[r] = 0;
    }

    const short8* bp = (const short8*)smem;
    const int bidx = l15 * 4 + (l4 ^ ((l15 >> 1) & 3));
    const f32x4 zero = {0.f, 0.f, 0.f, 0.f};

    for (int cc = 0; cc < NCHUNK; cc++) {
        // ---- stage CHUNK candidate encodings (XOR-swizzled), CHUNK==THREADS ----
        {
            __attribute__((aligned(16))) unsigned short be[32];
            build_b(coord, seg, cb + cc * CHUNK + tid, be);
            short8* wp = (short8*)smem;
            int swz = (tid >> 1) & 3;
#pragma unroll
            for (int kb = 0; kb < 4; kb++)
                wp[tid * 4 + (kb ^ swz)] = ((const short8*)be)[kb];
        }
        __syncthreads();

        // ---- sweep: per 32 cands: 2 ds_read_b128 + 4 MFMA + 8 max3 / 16 cmp-add ----
#pragma unroll 4
        for (int c0 = 0; c0 < CHUNK; c0 += 32) {
            short8 bA = bp[bidx + c0 * 4];
            short8 bB = bp[bidx + (c0 + 16) * 4];
            f32x4 dA0 = __builtin_amdgcn_mfma_f32_16x16x32_bf16(af0, bA, zero, 0, 0, 0);
            f32x4 dA1 = __builtin_amdgcn_mfma_f32_16x16x32_bf16(af1, bA, zero, 0, 0, 0);
            f32x4 dB0 = __builtin_amdgcn_mfma_f32_16x16x32_bf16(af0, bB, zero, 0, 0, 0);
            f32x4 dB1 = __builtin_amdgcn_mfma_f32_16x16x32_bf16(af1, bB, zero, 0, 0, 0);
            if (PASS1) {
#pragma unroll
                for (int r = 0; r < 4; r++) {
                    rmax0[r] = fmaxf(fmaxf(rmax0[r], dA0[r]), dB0[r]);
                    rmax1[r] = fmaxf(fmaxf(rmax1[r], dA1[r]), dB1[r]);
                }
            } else {
#pragma unroll
                for (int r = 0; r < 4; r++) {
                    cv0[r] += ((dA0[r] > thr0[r]) ? 1 : 0) + ((dB0[r] > thr0[r]) ? 1 : 0);
                    cv1[r] += ((dA1[r] > thr1[r]) ? 1 : 0) + ((dB1[r] > thr1[r]) ? 1 : 0);
                }
            }
        }
        __syncthreads();
    }

    // ---- reduce across the 16 column-lanes; write per-split partial ----
    const int row0 = rb + wave * RPW + l4 * 4;
    if (PASS1) {
#pragma unroll
        for (int m = 1; m < 16; m <<= 1)
#pragma unroll
            for (int r = 0; r < 4; r++) {
                rmax0[r] = fmaxf(rmax0[r], __shfl_xor(rmax0[r], m, 64));
                rmax1[r] = fmaxf(rmax1[r], __shfl_xor(rmax1[r], m, 64));
            }
        if (l15 == 0) {
#pragma unroll
            for (int r = 0; r < 4; r++) {
                smax_part[split * N_PTS + row0 + r]      = rmax0[r];
                smax_part[split * N_PTS + row0 + 16 + r] = rmax1[r];
            }
        }
    } else {
#pragma unroll
        for (int m = 1; m < 16; m <<= 1)
#pragma unroll
            for (int r = 0; r < 4; r++) {
                cv0[r] += __shfl_xor(cv0[r], m, 64);
                cv1[r] += __shfl_xor(cv1[r], m, 64);
            }
        if (l15 == 0) {
#pragma unroll
            for (int r = 0; r < 4; r++) {
                cnt_part[split * N_PTS + row0 + r]      = cv0[r];
                cnt_part[split * N_PTS + row0 + 16 + r] = cv1[r];
            }
        }
    }
}

__device__ __forceinline__ float waveReduceSum(float v) {
#pragma unroll
    for (int off = 32; off > 0; off >>= 1) v += __shfl_down(v, off, 64);
    return v;
}

// CE + masked accumulation; last block finalizes the loss (done-counter).
// accum: [0]=sum_main, [1]=cnt_main, [2]=sum_bnd, [3]=cnt_bnd
__global__ __launch_bounds__(256) void k_ce(const float* __restrict__ logits,
                                            const int* __restrict__ seg,
                                            const int* __restrict__ cnt_part,
                                            float* __restrict__ accum,
                                            unsigned* __restrict__ done,
                                            float* __restrict__ out) {
    const int i = blockIdx.x * 256 + threadIdx.x;
    float s_main = 0.f, n_main = 0.f, s_bnd = 0.f, n_bnd = 0.f;
    {
        int s = seg[i];
        bool valid = (s != -1);
        const float4* row4 = (const float4*)(logits + (size_t)i * NCLS);
        float a[NCLS];
        float4 v0 = row4[0], v1 = row4[1], v2 = row4[2], v3 = row4[3], v4 = row4[4];
        a[0]=v0.x; a[1]=v0.y; a[2]=v0.z; a[3]=v0.w;
        a[4]=v1.x; a[5]=v1.y; a[6]=v1.z; a[7]=v1.w;
        a[8]=v2.x; a[9]=v2.y; a[10]=v2.z; a[11]=v2.w;
        a[12]=v3.x; a[13]=v3.y; a[14]=v3.z; a[15]=v3.w;
        a[16]=v4.x; a[17]=v4.y; a[18]=v4.z; a[19]=v4.w;
        float m = a[0];
#pragma unroll
        for (int c = 1; c < NCLS; c++) m = fmaxf(m, a[c]);
        float se = 0.f;
#pragma unroll
        for (int c = 0; c < NCLS; c++) se += __expf(a[c] - m);
        int tgt = min(max(s, 0), NCLS - 1);
        float at = 0.f;
#pragma unroll
        for (int c = 0; c < NCLS; c++) at += (c == tgt) ? a[c] : 0.f;
        float logp = at - m - __logf(se);
        int cnt = 0;
#pragma unroll
        for (int sp = 0; sp < CSPLIT; sp++) cnt += cnt_part[sp * N_PTS + i];
        // cnt includes self exactly once; boundary iff rank of nearest diff < K
        bool bnd = valid && ((cnt - 1) < KNN);
        if (valid) { s_main = logp; n_main = 1.f; }
        if (bnd)   { s_bnd  = logp; n_bnd  = 1.f; }
    }
    s_main = waveReduceSum(s_main);
    n_main = waveReduceSum(n_main);
    s_bnd  = waveReduceSum(s_bnd);
    n_bnd  = waveReduceSum(n_bnd);
    if ((threadIdx.x & 63) == 0) {
        atomicAdd(&accum[0], s_main);
        atomicAdd(&accum[1], n_main);
        atomicAdd(&accum[2], s_bnd);
        atomicAdd(&accum[3], n_bnd);
    }
    __syncthreads();
    if (threadIdx.x == 0) {
        __threadfence();
        unsigned old = atomicAdd(done, 1u);
        if (old == gridDim.x - 1) {
            float sm = atomicAdd(&accum[0], 0.f);
            float cm = atomicAdd(&accum[1], 0.f);
            float sb = atomicAdd(&accum[2], 0.f);
            float cb = atomicAdd(&accum[3], 0.f);
            float main_loss = (cm > 0.f) ? (-sm / fmaxf(cm, 1.f)) : 0.f;
            float bnd_loss  = (cb > 0.f) ? (-sb / fmaxf(cb, 1.f)) : 0.f;
            out[0] = main_loss + BND_W * bnd_loss;
        }
    }
}

extern "C" void kernel_launch(void* const* d_in, const int* in_sizes, int n_in,
                              void* d_out, int out_size, void* d_ws, size_t ws_size,
                              hipStream_t stream) {
    const float* coord  = (const float*)d_in[0];
    const float* logits = (const float*)d_in[1];
    const int*   seg    = (const int*)d_in[2];
    (void)in_sizes; (void)n_in; (void)out_size; (void)ws_size;

    float*    smax_part = (float*)d_ws;                                   // [16][N] f32
    int*      cnt_part  = (int*)((char*)d_ws + CSPLIT * N_PTS * 4);       // [16][N] i32
    float*    accum     = (float*)((char*)d_ws + 2 * CSPLIT * N_PTS * 4); // 4 f32
    unsigned* done      = (unsigned*)((char*)d_ws + 2 * CSPLIT * N_PTS * 4 + 16);

    dim3 grid(RBLKS, CSPLIT);
    k_pass<true> <<<grid, THREADS, 0, stream>>>(coord, seg, smax_part, cnt_part, accum, done);
    k_pass<false><<<grid, THREADS, 0, stream>>>(coord, seg, smax_part, cnt_part, accum, done);
    k_ce         <<<N_PTS / 256, 256, 0, stream>>>(logits, seg, cnt_part, accum, done, (float*)d_out);
}